// Round 5
// baseline (289.703 us; speedup 1.0000x reference)
//
#include <hip/hip_runtime.h>
#include <hip/hip_cooperative_groups.h>
#include <math.h>

namespace cg = cooperative_groups;

// StatefulRosenberg R12: cooperative single-kernel; f0 read ONCE.
//
// R11 standing: k_chunk_sums ~13 us + k_emit ~36 us = ~49 us vs a 201 MB /
// 6 TB/s = ~33 us floor. The gap: an entire dispatch producing 8 KB of
// sums, plus k_emit re-reading f0 (LLC-hit but occupies issue/vmcnt depth).
// R12: one cooperative kernel. Phase A loads f0 (64 elem/thread, steps
// kept in st[8][8] registers), block total -> partial[1024] (8 KB),
// grid.sync(). Phase B: 64-wide row prefix, then 8 emit iterations that
// chain the row base through per-iteration block-scan totals (double-
// buffered LDS, 1 barrier/iter). Phase B touches only oq + wav.
//   - sizing is co-residency exact: bounds(256,4) => <=128 VGPR (est ~105)
//     => 4 blocks/CU => grid 1024. hipLaunchCooperativeKernel validates
//     and ERRORS (not deadlocks) if it can't fit; R11 two-kernel path kept
//     as fallback on launch error.
//   - no polling anywhere (R8's failure was acquire-spin thrash; this is
//     one validated grid barrier).
//   - no memset: every partial slot written pre-sync by its owning block.
// Kept lessons: loads hoisted ahead of scans (R9), regular wav stores
// (R9 nt-store write amplification), nt loads on read-once streams,
// f64 scan infra + f32 per-element accumulation after one f64 wrap.

constexpr int BATCH   = 16;
constexpr int T       = 1048576;
constexpr int THREADS = 256;
constexpr int VPT     = 8;                       // elements per thread per iteration
constexpr int ITERS   = 8;                       // iterations per block
constexpr int SUBCH   = THREADS * VPT;           // 2048 elements per iteration
constexpr int BLK_EL  = SUBCH * ITERS;           // 16384 elements per block
constexpr int BPR     = T / BLK_EL;              // 64 blocks per row
constexpr int NBLK    = BATCH * BPR;             // 1024 = 256 CU x 4 blocks/CU

#define INV_SR (1.0f / 48000.0f)

typedef float v4f __attribute__((ext_vector_type(4)));

__device__ __forceinline__ double tree8(const float* s) {
    return (((double)s[0] + (double)s[1]) + ((double)s[2] + (double)s[3]))
         + (((double)s[4] + (double)s[5]) + ((double)s[6] + (double)s[7]));
}

__global__ __launch_bounds__(THREADS, 4) void k_fused(
    const float* __restrict__ f0, const float* __restrict__ oq,
    const float* __restrict__ phase_state,
    float* __restrict__ wav, float* __restrict__ next_state,
    double* __restrict__ partial)
{
    const int bid  = blockIdx.x;
    const int row  = bid >> 6;            // / BPR
    const int sidx = bid & 63;            // block index within row
    const int lane = threadIdx.x & 63, wid = threadIdx.x >> 6;
    const size_t tb = (size_t)row * T + (size_t)sidx * BLK_EL
                    + (size_t)threadIdx.x * VPT;

    __shared__ double redS[THREADS / 64];
    __shared__ double wsS[2][THREADS / 64];
    __shared__ double prefS;

    // ---------------- Phase A: f0 -> registers, block total -> partial ----
    float st[ITERS][VPT];
    const v4f* fb = (const v4f*)(f0 + tb);
#pragma unroll
    for (int k = 0; k < ITERS; ++k) {
        v4f a = __builtin_nontemporal_load(fb + (size_t)k * (SUBCH / 4));
        v4f b = __builtin_nontemporal_load(fb + (size_t)k * (SUBCH / 4) + 1);
        st[k][0]=a.x*INV_SR; st[k][1]=a.y*INV_SR; st[k][2]=a.z*INV_SR; st[k][3]=a.w*INV_SR;
        st[k][4]=b.x*INV_SR; st[k][5]=b.y*INV_SR; st[k][6]=b.z*INV_SR; st[k][7]=b.w*INV_SR;
    }
    double ttot = 0.0;
#pragma unroll
    for (int k = 0; k < ITERS; ++k) ttot += tree8(st[k]);
#pragma unroll
    for (int off = 32; off > 0; off >>= 1)
        ttot += __shfl_down(ttot, off, 64);
    if (lane == 0) redS[wid] = ttot;
    __syncthreads();
    if (threadIdx.x == 0)
        partial[(row << 6) + sidx] = redS[0] + redS[1] + redS[2] + redS[3];

    cg::this_grid().sync();

    // ---------------- Phase B: row prefix, then emit 8 sub-chunks --------
    double pv = ((int)threadIdx.x < sidx)
              ? partial[(row << 6) + threadIdx.x] : 0.0;
#pragma unroll
    for (int off = 32; off > 0; off >>= 1)
        pv += __shfl_down(pv, off, 64);
    if (threadIdx.x == 0) prefS = pv + (double)phase_state[row];
    __syncthreads();
    double rowbase = prefS;   // running unwrapped base for this block

    const v4f* ob = (const v4f*)(oq + tb);
    v4f*       wb = (v4f*)(wav + tb);

#pragma unroll
    for (int k = 0; k < ITERS; ++k) {
        // oq load issued before the scan (latency hides under it, R9)
        v4f oa = __builtin_nontemporal_load(ob + (size_t)k * (SUBCH / 4));
        v4f obv = __builtin_nontemporal_load(ob + (size_t)k * (SUBCH / 4) + 1);

        double tsum = tree8(st[k]);
        double inc = tsum;
#pragma unroll
        for (int off = 1; off < 64; off <<= 1) {
            double n = __shfl_up(inc, off, 64);
            if (lane >= off) inc += n;
        }
        if (lane == 63) wsS[k & 1][wid] = inc;
        __syncthreads();

        double base = rowbase + (inc - tsum);
#pragma unroll
        for (int w = 0; w < THREADS / 64; ++w)
            if (w < wid) base += wsS[k & 1][w];

        // wrap thread base ONCE in f64; f32 accumulation per element
        // (max unwrapped < 1 + 8/48000 -> single fract suffices)
        float runf = (float)(base - floor(base));

        float o[VPT] = {oa.x, oa.y, oa.z, oa.w, obv.x, obv.y, obv.z, obv.w};
        float outv[VPT];
#pragma unroll
        for (int i = 0; i < VPT; ++i) {
            runf += st[k][i];
            float ph  = __builtin_amdgcn_fractf(runf);
            float oqv = o[i];
            float tp  = oqv * 0.66f;
            bool  is_rise  = ph < tp;
            bool  in_pulse = ph < oqv;
            float num = is_rise ? ph : (ph - tp);
            float den = is_rise ? fmaf(oqv, 0.66f, 1e-6f)    // tp + eps
                                : fmaf(oqv, 0.68f, 1e-6f);   // 2*tn + eps
            float rev = 0.5f * num * __builtin_amdgcn_rcpf(den);
            float c   = __builtin_amdgcn_cosf(rev);
            outv[i] = is_rise ? 0.5f * (1.0f - c) : (in_pulse ? c : 0.0f);
        }
        v4f v0; v0.x=outv[0]; v0.y=outv[1]; v0.z=outv[2]; v0.w=outv[3];
        v4f v1; v1.x=outv[4]; v1.y=outv[5]; v1.z=outv[6]; v1.w=outv[7];
        wb[(size_t)k * (SUBCH / 4)]     = v0;   // regular stores (R9 lesson)
        wb[(size_t)k * (SUBCH / 4) + 1] = v1;

        // advance row base by this sub-chunk's block total (uniform)
        rowbase += wsS[k & 1][0] + wsS[k & 1][1] + wsS[k & 1][2] + wsS[k & 1][3];
    }

    // next_state: unwrapped final phase of the row (last block, f64 path)
    if (sidx == 63 && threadIdx.x == 0)
        next_state[row] = (float)rowbase;
}

// ================= Fallback: R11 two-kernel path (proven, 174.8 us) ======
constexpr int VPT_FB    = 8;
constexpr int CHUNK_FB  = THREADS * VPT_FB;   // 2048
constexpr int NCHUNK_FB = T / CHUNK_FB;       // 512

__global__ __launch_bounds__(THREADS, 8) void k_chunk_sums(
    const float* __restrict__ f0, double* __restrict__ partial)
{
    const int chunk = blockIdx.x;
    const int row   = blockIdx.y;
    const v4f* base = (const v4f*)(f0 + (size_t)row * T
                     + (size_t)chunk * CHUNK_FB + (size_t)threadIdx.x * VPT_FB);
    v4f v0 = base[0], v1 = base[1];
    double s = ((double)(v0.x * INV_SR) + (double)(v0.y * INV_SR))
             + ((double)(v0.z * INV_SR) + (double)(v0.w * INV_SR))
             + ((double)(v1.x * INV_SR) + (double)(v1.y * INV_SR))
             + ((double)(v1.z * INV_SR) + (double)(v1.w * INV_SR));
#pragma unroll
    for (int off = 32; off > 0; off >>= 1)
        s += __shfl_down(s, off, 64);
    __shared__ double ws[THREADS / 64];
    const int lane = threadIdx.x & 63, wid = threadIdx.x >> 6;
    if (lane == 0) ws[wid] = s;
    __syncthreads();
    if (threadIdx.x == 0)
        partial[row * NCHUNK_FB + chunk] = ws[0] + ws[1] + ws[2] + ws[3];
}

__global__ __launch_bounds__(THREADS, 8) void k_emit(
    const float* __restrict__ f0, const float* __restrict__ oq,
    const double* __restrict__ partial, const float* __restrict__ phase_state,
    float* __restrict__ wav, float* __restrict__ next_state)
{
    const int chunk = blockIdx.x;
    const int row   = blockIdx.y;
    const int lane  = threadIdx.x & 63, wid = threadIdx.x >> 6;
    const size_t base_idx = (size_t)row * T + (size_t)chunk * CHUNK_FB
                          + (size_t)threadIdx.x * VPT_FB;

    __shared__ double rs[THREADS / 64];
    __shared__ double ws[THREADS / 64];

    const v4f* fb = (const v4f*)(f0 + base_idx);
    v4f f_0 = fb[0], f_1 = fb[1];
    const v4f* ob = (const v4f*)(oq + base_idx);
    v4f o_0 = __builtin_nontemporal_load(ob + 0);
    v4f o_1 = __builtin_nontemporal_load(ob + 1);
    double pv = 0.0;
    if ((int)threadIdx.x < chunk)       pv  = partial[row * NCHUNK_FB + threadIdx.x];
    if ((int)threadIdx.x + 256 < chunk) pv += partial[row * NCHUNK_FB + threadIdx.x + 256];
    const float pstate = phase_state[row];

    float st[VPT_FB];
    st[0]=f_0.x*INV_SR; st[1]=f_0.y*INV_SR; st[2]=f_0.z*INV_SR; st[3]=f_0.w*INV_SR;
    st[4]=f_1.x*INV_SR; st[5]=f_1.y*INV_SR; st[6]=f_1.z*INV_SR; st[7]=f_1.w*INV_SR;
    double tsum = tree8(st);

#pragma unroll
    for (int off = 32; off > 0; off >>= 1)
        pv += __shfl_down(pv, off, 64);
    if (lane == 0) rs[wid] = pv;

    double inc = tsum;
#pragma unroll
    for (int off = 1; off < 64; off <<= 1) {
        double n = __shfl_up(inc, off, 64);
        if (lane >= off) inc += n;
    }
    if (lane == 63) ws[wid] = inc;
    __syncthreads();

    const double chunkpref = rs[0] + rs[1] + rs[2] + rs[3];
    double run = (double)pstate + chunkpref + (inc - tsum);
#pragma unroll
    for (int w = 0; w < THREADS / 64; ++w)
        if (w < wid) run += ws[w];

    if (chunk == NCHUNK_FB - 1 && threadIdx.x == 0)
        next_state[row] = (float)((double)pstate + chunkpref
                                  + ws[0] + ws[1] + ws[2] + ws[3]);

    float runf = (float)(run - floor(run));

    float o[VPT_FB];
    o[0]=o_0.x; o[1]=o_0.y; o[2]=o_0.z; o[3]=o_0.w;
    o[4]=o_1.x; o[5]=o_1.y; o[6]=o_1.z; o[7]=o_1.w;

    float outv[VPT_FB];
#pragma unroll
    for (int i = 0; i < VPT_FB; ++i) {
        runf += st[i];
        float ph  = __builtin_amdgcn_fractf(runf);
        float oqv = o[i];
        float tp  = oqv * 0.66f;
        bool  is_rise  = ph < tp;
        bool  in_pulse = ph < oqv;
        float num = is_rise ? ph : (ph - tp);
        float den = is_rise ? fmaf(oqv, 0.66f, 1e-6f)
                            : fmaf(oqv, 0.68f, 1e-6f);
        float rev = 0.5f * num * __builtin_amdgcn_rcpf(den);
        float c   = __builtin_amdgcn_cosf(rev);
        outv[i] = is_rise ? 0.5f * (1.0f - c) : (in_pulse ? c : 0.0f);
    }

    v4f* wb = (v4f*)(wav + base_idx);
#pragma unroll
    for (int j = 0; j < VPT_FB / 4; ++j) {
        v4f vv;
        vv.x = outv[4 * j + 0]; vv.y = outv[4 * j + 1];
        vv.z = outv[4 * j + 2]; vv.w = outv[4 * j + 3];
        wb[j] = vv;
    }
}

extern "C" void kernel_launch(void* const* d_in, const int* in_sizes, int n_in,
                              void* d_out, int out_size, void* d_ws, size_t ws_size,
                              hipStream_t stream)
{
    const float* f0          = (const float*)d_in[0];
    const float* oq          = (const float*)d_in[1];
    const float* phase_state = (const float*)d_in[2];
    float* wav = (float*)d_out;
    float* ns  = wav + (size_t)BATCH * T;
    double* partial = (double*)d_ws;   // fused: 8 KB; fallback: 64 KB

    void* args[] = { (void*)&f0, (void*)&oq, (void*)&phase_state,
                     (void*)&wav, (void*)&ns, (void*)&partial };
    hipError_t e = hipLaunchCooperativeKernel((const void*)k_fused,
                                              dim3(NBLK), dim3(THREADS),
                                              args, 0, stream);
    if (e != hipSuccess) {
        // proven R11 two-kernel path
        dim3 grid(NCHUNK_FB, BATCH);
        k_chunk_sums<<<grid, THREADS, 0, stream>>>(f0, partial);
        k_emit<<<grid, THREADS, 0, stream>>>(f0, oq, partial, phase_state,
                                             wav, ns);
    }
}

// Round 6
// 177.874 us; speedup vs baseline: 1.6287x; 1.6287x over previous
//
#include <hip/hip_runtime.h>
#include <math.h>

// StatefulRosenberg R13: wave-independent k_emit via two-level partials.
//
// R12 post-mortem: grid.sync costs ~0.13 us/block on MI355X (R8 spin:
// 470us/4096blk = 0.115; R12 coop: 147us/1024blk = 0.143 -- two impls,
// same constant). Grid-wide sync with O(1000) blocks is structurally
// ~130 us here. Cooperative lane abandoned.
// Ledger: dur_us carries ~127 us fixed harness overhead (fills timed);
// controllable = ~49 us (sums 13 + emit 36) vs ~33 us traffic floor.
//
// R13 theory: k_emit's 3.7 TB/s (vs 6.3) comes from the per-block
// scan->LDS->__syncthreads critical path parking all 4 waves together.
// Fix: pass 1 writes per-512-elem group sums (p512) AND per-2048 chunk
// sums (p2048); each emit wave is then fully independent:
//   base = xor-butterfly reduce of <=512 p2048 (8 predicated L2 loads/lane)
//        + <=3 sibling p512 + own 64-lane shfl_up scan.
// NO LDS, NO barriers in k_emit. All f64 (assoc-order diffs ~1e-16).
//
// Kept lessons: loads hoisted ahead of scan work (R9), regular wav stores
// (R9: nt-store = +30 MB write amplification), nt loads only on read-once
// oq (f0 stays cached: pass 2 re-reads it from LLC), f64 scan infra +
// f32 per-element accumulation after one f64 wrap.
// Workspace 320 KB gated on ws_size; R11 path (proven 174.8) as fallback.

constexpr int BATCH   = 16;
constexpr int T       = 1048576;
constexpr int THREADS = 256;
constexpr int VPT     = 8;                 // elements per thread
constexpr int CHUNK   = THREADS * VPT;     // 2048
constexpr int NCHUNK  = T / CHUNK;         // 512 chunks per row
constexpr int NGRP    = NCHUNK * 4;        // 2048 512-elem groups per row

#define INV_SR (1.0f / 48000.0f)

typedef float v4f __attribute__((ext_vector_type(4)));

__device__ __forceinline__ double tree8(const float* s) {
    return (((double)s[0] + (double)s[1]) + ((double)s[2] + (double)s[3]))
         + (((double)s[4] + (double)s[5]) + ((double)s[6] + (double)s[7]));
}

// ---------------- Pass 1: group (512) + chunk (2048) fp64 sums ----------
__global__ __launch_bounds__(THREADS, 8) void k_sums(
    const float* __restrict__ f0, double* __restrict__ p512,
    double* __restrict__ p2048)
{
    const int c    = blockIdx.x;
    const int row  = blockIdx.y;
    const int lane = threadIdx.x & 63, wid = threadIdx.x >> 6;
    const v4f* base = (const v4f*)(f0 + (size_t)row * T
                     + (size_t)c * CHUNK + (size_t)threadIdx.x * VPT);
    v4f v0 = base[0], v1 = base[1];          // regular loads: warm LLC for pass 2
    float st[VPT];
    st[0]=v0.x*INV_SR; st[1]=v0.y*INV_SR; st[2]=v0.z*INV_SR; st[3]=v0.w*INV_SR;
    st[4]=v1.x*INV_SR; st[5]=v1.y*INV_SR; st[6]=v1.z*INV_SR; st[7]=v1.w*INV_SR;
    double s = tree8(st);
#pragma unroll
    for (int off = 32; off > 0; off >>= 1)
        s += __shfl_xor(s, off, 64);         // all lanes hold wave (group) sum
    if (lane == 0) p512[(size_t)row * NGRP + c * 4 + wid] = s;
    __shared__ double ws[THREADS / 64];
    if (lane == 0) ws[wid] = s;
    __syncthreads();
    if (threadIdx.x == 0)
        p2048[(size_t)row * NCHUNK + c] = (ws[0] + ws[1]) + (ws[2] + ws[3]);
}

// ---------------- Pass 2: wave-independent prefix + emit -----------------
__global__ __launch_bounds__(THREADS, 8) void k_emit(
    const float* __restrict__ f0, const float* __restrict__ oq,
    const double* __restrict__ p512, const double* __restrict__ p2048,
    const float* __restrict__ phase_state,
    float* __restrict__ wav, float* __restrict__ next_state)
{
    const int c    = blockIdx.x;
    const int row  = blockIdx.y;
    const int lane = threadIdx.x & 63, wid = threadIdx.x >> 6;
    const size_t base_idx = (size_t)row * T + (size_t)c * CHUNK
                          + (size_t)wid * 512 + (size_t)lane * VPT;

    // ---- all global loads issued up front (latency hides under prefix math)
    const v4f* fb = (const v4f*)(f0 + base_idx);
    v4f f_0 = fb[0], f_1 = fb[1];                       // LLC-hot re-read
    const v4f* ob = (const v4f*)(oq + base_idx);
    v4f o_0 = __builtin_nontemporal_load(ob + 0);
    v4f o_1 = __builtin_nontemporal_load(ob + 1);

    // chunk prefix: <=512 p2048 values, 8 predicated L2/L1-hot loads per lane
    const double* pp = p2048 + (size_t)row * NCHUNK;
    double pv = 0.0;
#pragma unroll
    for (int k = 0; k < 8; ++k) {
        int j = lane + 64 * k;
        if (j < c) pv += pp[j];
    }
    // sibling groups within this chunk (uniform per wave, broadcast loads)
    const double* sp = p512 + (size_t)row * NGRP + (size_t)c * 4;
    double sib = 0.0;
    if (wid > 0) sib += sp[0];
    if (wid > 1) sib += sp[1];
    if (wid > 2) sib += sp[2];
    const float pstate = phase_state[row];

    // ---- f32 steps + lane f64 sum ----
    float st[VPT];
    st[0]=f_0.x*INV_SR; st[1]=f_0.y*INV_SR; st[2]=f_0.z*INV_SR; st[3]=f_0.w*INV_SR;
    st[4]=f_1.x*INV_SR; st[5]=f_1.y*INV_SR; st[6]=f_1.z*INV_SR; st[7]=f_1.w*INV_SR;
    double tsum = tree8(st);

    // ---- xor-butterfly: every lane gets chunkpref (no broadcast needed)
#pragma unroll
    for (int off = 32; off > 0; off >>= 1)
        pv += __shfl_xor(pv, off, 64);

    // ---- 64-lane inclusive scan of lane sums (wave-local, no LDS/barrier)
    double inc = tsum;
#pragma unroll
    for (int off = 1; off < 64; off <<= 1) {
        double n = __shfl_up(inc, off, 64);
        if (lane >= off) inc += n;
    }

    const double base = (double)pstate + pv + sib;
    const double run  = base + (inc - tsum);

    // next_state: unwrapped final row phase = base + inclusive total of the
    // very last group (c=511, wid=3, lane=63)
    if (c == NCHUNK - 1 && wid == 3 && lane == 63)
        next_state[row] = (float)(base + inc);

    // wrap thread base ONCE in f64; f32 per-element accumulation
    // (max unwrapped < 1 + 8/48000 -> single fract suffices)
    float runf = (float)(run - floor(run));

    float o[VPT];
    o[0]=o_0.x; o[1]=o_0.y; o[2]=o_0.z; o[3]=o_0.w;
    o[4]=o_1.x; o[5]=o_1.y; o[6]=o_1.z; o[7]=o_1.w;

    float outv[VPT];
#pragma unroll
    for (int i = 0; i < VPT; ++i) {
        runf += st[i];
        float ph  = __builtin_amdgcn_fractf(runf);     // wrapped phase [0,1)
        float oqv = o[i];
        float tp  = oqv * 0.66f;
        bool  is_rise  = ph < tp;
        bool  in_pulse = ph < oqv;
        float num = is_rise ? ph : (ph - tp);
        float den = is_rise ? fmaf(oqv, 0.66f, 1e-6f)    // tp + eps
                            : fmaf(oqv, 0.68f, 1e-6f);   // 2*tn + eps
        float rev = 0.5f * num * __builtin_amdgcn_rcpf(den);
        float c2  = __builtin_amdgcn_cosf(rev);
        outv[i] = is_rise ? 0.5f * (1.0f - c2) : (in_pulse ? c2 : 0.0f);
    }

    v4f* wb = (v4f*)(wav + base_idx);
    v4f w0; w0.x=outv[0]; w0.y=outv[1]; w0.z=outv[2]; w0.w=outv[3];
    v4f w1; w1.x=outv[4]; w1.y=outv[5]; w1.z=outv[6]; w1.w=outv[7];
    wb[0] = w0;           // regular stores: L2 merges partial lines (R9)
    wb[1] = w1;
}

// ================= Fallback: R11 two-kernel path (proven, 174.8 us) ======
__global__ __launch_bounds__(THREADS, 8) void k_chunk_sums_fb(
    const float* __restrict__ f0, double* __restrict__ partial)
{
    const int chunk = blockIdx.x;
    const int row   = blockIdx.y;
    const v4f* base = (const v4f*)(f0 + (size_t)row * T
                     + (size_t)chunk * CHUNK + (size_t)threadIdx.x * VPT);
    v4f v0 = base[0], v1 = base[1];
    float st[VPT];
    st[0]=v0.x*INV_SR; st[1]=v0.y*INV_SR; st[2]=v0.z*INV_SR; st[3]=v0.w*INV_SR;
    st[4]=v1.x*INV_SR; st[5]=v1.y*INV_SR; st[6]=v1.z*INV_SR; st[7]=v1.w*INV_SR;
    double s = tree8(st);
#pragma unroll
    for (int off = 32; off > 0; off >>= 1)
        s += __shfl_down(s, off, 64);
    __shared__ double ws[THREADS / 64];
    const int lane = threadIdx.x & 63, wid = threadIdx.x >> 6;
    if (lane == 0) ws[wid] = s;
    __syncthreads();
    if (threadIdx.x == 0)
        partial[row * NCHUNK + chunk] = ws[0] + ws[1] + ws[2] + ws[3];
}

__global__ __launch_bounds__(THREADS, 8) void k_emit_fb(
    const float* __restrict__ f0, const float* __restrict__ oq,
    const double* __restrict__ partial, const float* __restrict__ phase_state,
    float* __restrict__ wav, float* __restrict__ next_state)
{
    const int chunk = blockIdx.x;
    const int row   = blockIdx.y;
    const int lane  = threadIdx.x & 63, wid = threadIdx.x >> 6;
    const size_t base_idx = (size_t)row * T + (size_t)chunk * CHUNK
                          + (size_t)threadIdx.x * VPT;
    __shared__ double rs[THREADS / 64];
    __shared__ double ws[THREADS / 64];

    const v4f* fb = (const v4f*)(f0 + base_idx);
    v4f f_0 = fb[0], f_1 = fb[1];
    const v4f* ob = (const v4f*)(oq + base_idx);
    v4f o_0 = __builtin_nontemporal_load(ob + 0);
    v4f o_1 = __builtin_nontemporal_load(ob + 1);
    double pv = 0.0;
    if ((int)threadIdx.x < chunk)       pv  = partial[row * NCHUNK + threadIdx.x];
    if ((int)threadIdx.x + 256 < chunk) pv += partial[row * NCHUNK + threadIdx.x + 256];
    const float pstate = phase_state[row];

    float st[VPT];
    st[0]=f_0.x*INV_SR; st[1]=f_0.y*INV_SR; st[2]=f_0.z*INV_SR; st[3]=f_0.w*INV_SR;
    st[4]=f_1.x*INV_SR; st[5]=f_1.y*INV_SR; st[6]=f_1.z*INV_SR; st[7]=f_1.w*INV_SR;
    double tsum = tree8(st);
#pragma unroll
    for (int off = 32; off > 0; off >>= 1)
        pv += __shfl_down(pv, off, 64);
    if (lane == 0) rs[wid] = pv;
    double inc = tsum;
#pragma unroll
    for (int off = 1; off < 64; off <<= 1) {
        double n = __shfl_up(inc, off, 64);
        if (lane >= off) inc += n;
    }
    if (lane == 63) ws[wid] = inc;
    __syncthreads();
    const double chunkpref = rs[0] + rs[1] + rs[2] + rs[3];
    double run = (double)pstate + chunkpref + (inc - tsum);
#pragma unroll
    for (int w = 0; w < THREADS / 64; ++w)
        if (w < wid) run += ws[w];
    if (chunk == NCHUNK - 1 && threadIdx.x == 0)
        next_state[row] = (float)((double)pstate + chunkpref
                                  + ws[0] + ws[1] + ws[2] + ws[3]);
    float runf = (float)(run - floor(run));
    float o[VPT];
    o[0]=o_0.x; o[1]=o_0.y; o[2]=o_0.z; o[3]=o_0.w;
    o[4]=o_1.x; o[5]=o_1.y; o[6]=o_1.z; o[7]=o_1.w;
    float outv[VPT];
#pragma unroll
    for (int i = 0; i < VPT; ++i) {
        runf += st[i];
        float ph  = __builtin_amdgcn_fractf(runf);
        float oqv = o[i];
        float tp  = oqv * 0.66f;
        bool  is_rise  = ph < tp;
        bool  in_pulse = ph < oqv;
        float num = is_rise ? ph : (ph - tp);
        float den = is_rise ? fmaf(oqv, 0.66f, 1e-6f)
                            : fmaf(oqv, 0.68f, 1e-6f);
        float rev = 0.5f * num * __builtin_amdgcn_rcpf(den);
        float c2  = __builtin_amdgcn_cosf(rev);
        outv[i] = is_rise ? 0.5f * (1.0f - c2) : (in_pulse ? c2 : 0.0f);
    }
    v4f* wb = (v4f*)(wav + base_idx);
    v4f w0; w0.x=outv[0]; w0.y=outv[1]; w0.z=outv[2]; w0.w=outv[3];
    v4f w1; w1.x=outv[4]; w1.y=outv[5]; w1.z=outv[6]; w1.w=outv[7];
    wb[0] = w0; wb[1] = w1;
}

extern "C" void kernel_launch(void* const* d_in, const int* in_sizes, int n_in,
                              void* d_out, int out_size, void* d_ws, size_t ws_size,
                              hipStream_t stream)
{
    const float* f0          = (const float*)d_in[0];
    const float* oq          = (const float*)d_in[1];
    const float* phase_state = (const float*)d_in[2];
    float* wav = (float*)d_out;
    float* ns  = wav + (size_t)BATCH * T;

    const size_t need = (size_t)BATCH * NGRP * sizeof(double)      // p512 256 KB
                      + (size_t)BATCH * NCHUNK * sizeof(double);   // p2048 64 KB
    dim3 grid(NCHUNK, BATCH);
    if (ws_size >= need) {
        double* p512  = (double*)d_ws;
        double* p2048 = p512 + (size_t)BATCH * NGRP;
        k_sums<<<grid, THREADS, 0, stream>>>(f0, p512, p2048);
        k_emit<<<grid, THREADS, 0, stream>>>(f0, oq, p512, p2048, phase_state,
                                             wav, ns);
    } else {
        double* partial = (double*)d_ws;   // 64 KB
        k_chunk_sums_fb<<<grid, THREADS, 0, stream>>>(f0, partial);
        k_emit_fb<<<grid, THREADS, 0, stream>>>(f0, oq, partial, phase_state,
                                                wav, ns);
    }
}